// Round 9
// baseline (186.972 us; speedup 1.0000x reference)
//
#include <hip/hip_runtime.h>
#include <hip/hip_bf16.h>

#define DEV_INLINE __device__ __forceinline__

constexpr int Nn   = 10000;     // nodes per batch
constexpr int NT   = 20000;     // B*N
constexpr int Me   = 320000;    // template edges
constexpr float NEG = 0.2f;

typedef float  f32x4  __attribute__((ext_vector_type(4)));
typedef short  bf16x8 __attribute__((ext_vector_type(8)));

DEV_INLINE float leaky(float x){ return x >= 0.f ? x : NEG*x; }

DEV_INLINE ushort f2bf(float v){
  __hip_bfloat16 h = __float2bfloat16(v);
  return *reinterpret_cast<ushort*>(&h);
}
DEV_INLINE float bf2f(ushort u){
  uint x = ((uint)u) << 16;
  return __uint_as_float(x);
}
DEV_INLINE float sel4(float4 w, int h){
  return h < 2 ? (h == 0 ? w.x : w.y) : (h == 2 ? w.z : w.w);
}
DEV_INLINE float red16(float v){
  v += __shfl_xor(v, 1); v += __shfl_xor(v, 2);
  v += __shfl_xor(v, 4); v += __shfl_xor(v, 8);
  return v;
}
DEV_INLINE float red32(float v){
  v += __shfl_xor(v, 1); v += __shfl_xor(v, 2);
  v += __shfl_xor(v, 4); v += __shfl_xor(v, 8);
  v += __shfl_xor(v, 16);
  return v;
}

// ---------------- generic small MLP stage: out[2*OD] = act(in[2,K] @ W[K,OD] + b) ----------------
template<int K>
__global__ __launch_bounds__(256) void k_mlp(const float* __restrict__ in,
    const float* __restrict__ W, const float* __restrict__ bias,
    float* __restrict__ out, int OD, int doAct){
  int wave = threadIdx.x >> 6, lane = threadIdx.x & 63;
  int o = blockIdx.x*4 + wave;
  if (o >= 2*OD) return;
  int b = (o >= OD) ? 1 : 0;
  int j = o - b*OD;
  const float* __restrict__ ip = in + b*K;
  float acc = 0.f;
  #pragma unroll 2
  for (int k = lane; k < K; k += 64) acc += ip[k] * W[(size_t)k*OD + j];
  #pragma unroll
  for (int off = 32; off; off >>= 1) acc += __shfl_xor(acc, off);
  if (lane == 0){
    float v = acc + (bias ? bias[j] : 0.f);
    out[o] = doAct ? leaky(v) : v;
  }
}

// ---------------- zero int buffer ----------------
__global__ __launch_bounds__(256) void k_zero(int* __restrict__ p, int n){
  int i = blockIdx.x*256 + threadIdx.x;
  if (i < n) p[i] = 0;
}

// ---------------- ht0(bf16) = x @ gw0[:64,:] + styleW0[b], fused layer-0 logits ----------------
__global__ __launch_bounds__(256) void k_ht0(const float* __restrict__ x,
    const float* __restrict__ gw0, const float* __restrict__ styleW0,
    const float* __restrict__ a_s, const float* __restrict__ a_d,
    ushort* __restrict__ ht0, float* __restrict__ alS, float* __restrict__ alD){
  __shared__ float wl[64][128];
  __shared__ float xl[32][64];
  __shared__ float sw[2][128];
  __shared__ float stycS[2][4], stycD[2][4];
  int t = threadIdx.x;
  for (int i=t; i<64*128; i+=256) wl[i>>7][i&127] = gw0[i];
  if (t < 256) sw[t>>7][t&127] = styleW0[t];
  int row0 = blockIdx.x*32;
  for (int i=t; i<32*64; i+=256){
    int r = i>>6, c = i&63; int gr = row0 + r;
    xl[r][c] = (gr < Nn) ? x[gr*64 + c] : 0.f;
  }
  __syncthreads();
  int c = t & 127, rh = t >> 7, lane = t & 63;
  float as_c = a_s[c], ad_c = a_d[c];
  int h = c >> 5;

  // style-const logits per (batch, head) -- threads t<128 cover all 128 cols
  if (t < 128){
    float v0s = sw[0][c]*as_c, v0d = sw[0][c]*ad_c;
    float v1s = sw[1][c]*as_c, v1d = sw[1][c]*ad_c;
    v0s = red32(v0s); v0d = red32(v0d);
    v1s = red32(v1s); v1d = red32(v1d);
    if ((lane & 31) == 0){
      stycS[0][h] = v0s; stycD[0][h] = v0d;
      stycS[1][h] = v1s; stycD[1][h] = v1d;
    }
  }

  float acc[16];
  #pragma unroll
  for (int i=0;i<16;i++) acc[i]=0.f;
  for (int k=0;k<64;k++){
    float w = wl[k][c];
    #pragma unroll
    for (int i=0;i<16;i++) acc[i] += xl[rh+2*i][k]*w;
  }
  __syncthreads();   // stycS/stycD visible
  float s0 = sw[0][c], s1 = sw[1][c];
  #pragma unroll
  for (int i=0;i<16;i++){
    int gr = row0 + rh + 2*i;
    if (gr < Nn){
      ht0[(size_t)gr*128 + c]      = f2bf(acc[i] + s0);
      ht0[(size_t)(Nn+gr)*128 + c] = f2bf(acc[i] + s1);
    }
    // fused logits: reduce acc[i]*a over this head's 32 lanes
    float vs = acc[i]*as_c, vd = acc[i]*ad_c;
    vs = red32(vs); vd = red32(vd);
    if ((lane & 31) == 0 && gr < Nn){
      alS[(size_t)gr*4 + h]      = vs + stycS[0][h];
      alD[(size_t)gr*4 + h]      = vd + stycD[0][h];
      alS[(size_t)(Nn+gr)*4 + h] = vs + stycS[1][h];
      alD[(size_t)(Nn+gr)*4 + h] = vd + stycD[1][h];
    }
  }
}

// ---- MFMA matmul + fused attention logits ----
template<int NCOL, int LDO, int NF, int NHEAD>
__global__ __launch_bounds__(256) void k_mm_mfma(const ushort* __restrict__ A,
    const float* __restrict__ W, ushort* __restrict__ out,
    const float* __restrict__ a_s, const float* __restrict__ a_d,
    float* __restrict__ alS, float* __restrict__ alD, int M){
  constexpr int NCOLP = NF*16;
  __shared__ ushort bt[NCOLP*128];  // Bt[c][k], XOR-swizzled
  int t = threadIdx.x;
  int wid = t >> 6, lane = t & 63, l15 = lane & 15, g = lane >> 4;
  int mbase = blockIdx.x*128 + wid*32;

  bf16x8 afr[2][4];
  #pragma unroll
  for (int mf=0; mf<2; mf++){
    int row = mbase + mf*16 + l15;
    int rc = row < M ? row : M-1;
    const ushort* ap = A + (size_t)rc*128 + g*8;
    #pragma unroll
    for (int ks=0; ks<4; ks++)
      afr[mf][ks] = *(const bf16x8*)(ap + ks*32);
  }

  for (int idx = t; idx < 128*NCOLP; idx += 256){
    int k = idx / NCOLP, c = idx % NCOLP;
    float v = (c < NCOL) ? W[k*NCOL + c] : 0.f;
    uint byte = ((uint)(c*128 + k) << 1) ^ ((uint)(c&7) << 4);
    *(ushort*)((char*)bt + byte) = f2bf(v);
  }
  __syncthreads();

  f32x4 acc[2][NF];
  #pragma unroll
  for (int mf=0; mf<2; mf++)
    #pragma unroll
    for (int nf=0; nf<NF; nf++) acc[mf][nf] = (f32x4){0.f,0.f,0.f,0.f};

  #pragma unroll
  for (int ks=0; ks<4; ks++){
    int kb = ks*32 + g*8;
    bf16x8 bfr[NF];
    #pragma unroll
    for (int nf=0; nf<NF; nf++){
      int c = nf*16 + l15;
      uint byte = ((uint)(c*128 + kb) << 1) ^ ((uint)(c&7) << 4);
      bfr[nf] = *(const bf16x8*)((const char*)bt + byte);
    }
    #pragma unroll
    for (int mf=0; mf<2; mf++)
      #pragma unroll
      for (int nf=0; nf<NF; nf++)
        acc[mf][nf] = __builtin_amdgcn_mfma_f32_16x16x32_bf16(
            afr[mf][ks], bfr[nf], acc[mf][nf], 0, 0, 0);
  }

  // C/D layout: col = lane&15, row = (lane>>4)*4 + r
  #pragma unroll
  for (int mf=0; mf<2; mf++){
    int rbase = mbase + mf*16 + g*4;
    #pragma unroll
    for (int nf=0; nf<NF; nf++){
      int c = nf*16 + l15;
      if (c < LDO){
        #pragma unroll
        for (int r=0; r<4; r++){
          int row = rbase + r;
          if (row < M) out[(size_t)row*LDO + c] = (c < NCOL) ? f2bf(acc[mf][nf][r]) : (ushort)0;
        }
      }
    }
  }

  // fused per-row attention logits
  float as_v[NF], ad_v[NF];
  #pragma unroll
  for (int nf=0; nf<NF; nf++){
    int c = nf*16 + l15;
    as_v[nf] = (c < NCOL) ? a_s[c] : 0.f;
    ad_v[nf] = (c < NCOL) ? a_d[c] : 0.f;
  }
  #pragma unroll
  for (int mf=0; mf<2; mf++){
    #pragma unroll
    for (int r=0; r<4; r++){
      int row = mbase + mf*16 + g*4 + r;
      if (NHEAD == 4){
        float ps0 = acc[mf][0][r]*as_v[0] + acc[mf][1][r]*as_v[1];
        float ps1 = acc[mf][2][r]*as_v[2] + acc[mf][3][r]*as_v[3];
        float ps2 = acc[mf][4][r]*as_v[4] + acc[mf][5][r]*as_v[5];
        float ps3 = acc[mf][6][r]*as_v[6] + acc[mf][7][r]*as_v[7];
        float pd0 = acc[mf][0][r]*ad_v[0] + acc[mf][1][r]*ad_v[1];
        float pd1 = acc[mf][2][r]*ad_v[2] + acc[mf][3][r]*ad_v[3];
        float pd2 = acc[mf][4][r]*ad_v[4] + acc[mf][5][r]*ad_v[5];
        float pd3 = acc[mf][6][r]*ad_v[6] + acc[mf][7][r]*ad_v[7];
        ps0 = red16(ps0); ps1 = red16(ps1); ps2 = red16(ps2); ps3 = red16(ps3);
        pd0 = red16(pd0); pd1 = red16(pd1); pd2 = red16(pd2); pd3 = red16(pd3);
        if (l15 == 0 && row < M){
          *(float4*)(alS + (size_t)row*4) = make_float4(ps0, ps1, ps2, ps3);
          *(float4*)(alD + (size_t)row*4) = make_float4(pd0, pd1, pd2, pd3);
        }
      } else {
        float ps = 0.f, pd = 0.f;
        #pragma unroll
        for (int nf=0; nf<NF; nf++){
          ps += acc[mf][nf][r]*as_v[nf];
          pd += acc[mf][nf][r]*ad_v[nf];
        }
        ps = red16(ps); pd = red16(pd);
        if (l15 == 0 && row < M){
          alS[row] = ps; alD[row] = pd;
        }
      }
    }
  }
}

// ---------------- CSR build (TEMPLATE graph only) ----------------
__global__ void k_hist(const int* __restrict__ eidx, int* __restrict__ cnt){
  int e = blockIdx.x*256 + threadIdx.x;
  if (e >= Me) return;
  atomicAdd(&cnt[eidx[Me + e]], 1);
}

// single-block exclusive scan of cnt[Nn] -> row_start AND cursor (copy)
__global__ __launch_bounds__(1024) void k_scan(const int* __restrict__ cnt,
    int* __restrict__ row_start, int* __restrict__ cursor){
  __shared__ int wtot[16];
  int t = threadIdx.x, lane = t & 63, w = t >> 6;
  int base = t*10;
  int pre[10]; int sum = 0;
  #pragma unroll
  for (int q=0;q<10;q++){
    int i = base+q;
    int v = (i < Nn) ? cnt[i] : 0;
    pre[q] = sum; sum += v;
  }
  int incl = sum;
  #pragma unroll
  for (int d=1; d<64; d<<=1){
    int y = __shfl_up(incl, d);
    if (lane >= d) incl += y;
  }
  if (lane == 63) wtot[w] = incl;
  __syncthreads();
  int wbase = 0;
  #pragma unroll
  for (int k=0;k<16;k++) wbase += (k < w) ? wtot[k] : 0;
  int excl = wbase + incl - sum;
  #pragma unroll
  for (int q=0;q<10;q++){
    int i = base+q;
    if (i < Nn){ row_start[i] = excl + pre[q]; cursor[i] = excl + pre[q]; }
  }
  if (t == 1023) row_start[Nn] = excl + sum;
}

__global__ void k_scatter(const int* __restrict__ eidx,
    int* __restrict__ cursor, ushort* __restrict__ csr){
  int e = blockIdx.x*256 + threadIdx.x;
  if (e >= Me) return;
  int s = eidx[e], d = eidx[Me + e];
  int p = atomicAdd(&cursor[d], 1);
  csr[p] = (ushort)s;
}

// ---------------- GAT aggregation layer 0/1, bf16 gathers, paired cols ----------------
__global__ __launch_bounds__(256) void k_gat128(const ushort* __restrict__ ht,
    const float* __restrict__ alS, const float* __restrict__ alD,
    const int* __restrict__ row_start, const ushort* __restrict__ csr,
    const float* __restrict__ gb, const float* __restrict__ lng,
    const float* __restrict__ lnb, ushort* __restrict__ outH, int n){
  __shared__ float4 wbuf[4][64];
  __shared__ int    sbuf[4][64];
  int wave = threadIdx.x >> 6, lane = threadIdx.x & 63;
  int dd = blockIdx.x*4 + wave;
  if (dd >= n) return;
  int tr  = (dd >= Nn) ? dd - Nn : dd;
  int off = (dd >= Nn) ? Nn : 0;
  int c0 = lane*2;
  int h  = lane >> 4;
  float4 ald4 = *(const float4*)(alD + dd*4);
  int begin = row_start[tr], end = row_start[tr+1];

  // self-loop term
  float4 asl = *(const float4*)(alS + dd*4);
  float4 wsl;
  wsl.x = __expf(leaky(asl.x + ald4.x));
  wsl.y = __expf(leaky(asl.y + ald4.y));
  wsl.z = __expf(leaky(asl.z + ald4.z));
  wsl.w = __expf(leaky(asl.w + ald4.w));
  float es = sel4(wsl, h);
  uint sv0 = *(const uint*)(ht + (size_t)dd*128 + c0);
  float den  = es;
  float acc0 = es * bf2f((ushort)(sv0 & 0xffff));
  float acc1 = es * bf2f((ushort)(sv0 >> 16));

  const ushort* __restrict__ htp = ht + c0;

  for (int j = begin; j < end; j += 64){
    int nc = min(64, end - j);
    // phase A: one edge per lane -> 4-head weights into wave-private LDS
    if (lane < nc){
      int s = (int)csr[j + lane] + off;
      float4 as4 = *(const float4*)(alS + s*4);
      float4 w;
      w.x = __expf(leaky(as4.x + ald4.x));
      w.y = __expf(leaky(as4.y + ald4.y));
      w.z = __expf(leaky(as4.z + ald4.z));
      w.w = __expf(leaky(as4.w + ald4.w));
      wbuf[wave][lane] = w;
      sbuf[wave][lane] = s;
    }
    // phase B: column-parallel FMA (LDS reads broadcast)
    int q = 0;
    for (; q + 8 <= nc; q += 8){
      int sv[8]; float4 wv[8];
      #pragma unroll
      for (int u=0;u<8;u++){ sv[u] = sbuf[wave][q+u]; wv[u] = wbuf[wave][q+u]; }
      uint hv[8];
      #pragma unroll
      for (int u=0;u<8;u++) hv[u] = *(const uint*)(htp + (size_t)sv[u]*128);
      #pragma unroll
      for (int u=0;u<8;u++){
        float e = sel4(wv[u], h);
        den  += e;
        acc0 += e * bf2f((ushort)(hv[u] & 0xffff));
        acc1 += e * bf2f((ushort)(hv[u] >> 16));
      }
    }
    for (; q < nc; q++){
      int s = sbuf[wave][q];
      float e = sel4(wbuf[wave][q], h);
      uint hv = *(const uint*)(htp + (size_t)s*128);
      den  += e;
      acc0 += e * bf2f((ushort)(hv & 0xffff));
      acc1 += e * bf2f((ushort)(hv >> 16));
    }
  }
  float idn = 1.f / (den + 1e-16f);
  float v0 = acc0*idn + gb[c0];
  float v1 = acc1*idn + gb[c0+1];

  // LayerNorm over 128 features held by this wave (2 per lane)
  float sum = v0 + v1, sq = v0*v0 + v1*v1;
  #pragma unroll
  for (int offx = 32; offx; offx >>= 1){
    sum += __shfl_xor(sum, offx);
    sq  += __shfl_xor(sq,  offx);
  }
  float mu  = sum * (1.f/128.f);
  float var = sq  * (1.f/128.f) - mu*mu;
  float inv = rsqrtf(var + 1e-5f);
  float y0 = (v0 - mu)*inv*lng[c0]   + lnb[c0];
  float y1 = (v1 - mu)*inv*lng[c0+1] + lnb[c0+1];
  uint ow = (uint)f2bf(leaky(y0)) | ((uint)f2bf(leaky(y1)) << 16);
  *(uint*)(outH + (size_t)dd*128 + c0) = ow;
}

// ---------------- GAT output layer (1 head, 67 cols), bf16 gathers + residual ----------------
__global__ __launch_bounds__(256) void k_gat_out(const ushort* __restrict__ ht2,
    const float* __restrict__ alS, const float* __restrict__ alD,
    const int* __restrict__ row_start, const ushort* __restrict__ csr,
    const float* __restrict__ gb2, const float* __restrict__ x,
    const float* __restrict__ pos, float* __restrict__ out, int n){
  __shared__ float wbuf[4][64];
  __shared__ int   sbuf[4][64];
  int wave = threadIdx.x >> 6, lane = threadIdx.x & 63;
  int dd = blockIdx.x*4 + wave;
  if (dd >= n) return;
  int tr  = (dd >= Nn) ? dd - Nn : dd;
  int off = (dd >= Nn) ? Nn : 0;
  int c0 = lane*2;
  bool act = (c0 < 67);             // lane < 34
  float ald = alD[dd];
  int begin = row_start[tr], end = row_start[tr+1];

  // self-loop term
  float wsl = __expf(leaky(alS[dd] + ald));
  float den  = wsl;
  uint sv0 = act ? *(const uint*)(ht2 + (size_t)dd*68 + c0) : 0u;
  float acc0 = wsl * bf2f((ushort)(sv0 & 0xffff));
  float acc1 = wsl * bf2f((ushort)(sv0 >> 16));

  const ushort* __restrict__ h2p = ht2 + c0;

  for (int j = begin; j < end; j += 64){
    int nc = min(64, end - j);
    if (lane < nc){
      int s = (int)csr[j + lane] + off;
      wbuf[wave][lane] = __expf(leaky(alS[s] + ald));
      sbuf[wave][lane] = s;
    }
    int q = 0;
    for (; q + 8 <= nc; q += 8){
      int sv[8]; float wv[8];
      #pragma unroll
      for (int u=0;u<8;u++){ sv[u] = sbuf[wave][q+u]; wv[u] = wbuf[wave][q+u]; }
      uint hv[8];
      #pragma unroll
      for (int u=0;u<8;u++) hv[u] = act ? *(const uint*)(h2p + (size_t)sv[u]*68) : 0u;
      #pragma unroll
      for (int u=0;u<8;u++){
        den  += wv[u];
        acc0 += wv[u] * bf2f((ushort)(hv[u] & 0xffff));
        acc1 += wv[u] * bf2f((ushort)(hv[u] >> 16));
      }
    }
    for (; q < nc; q++){
      int s = sbuf[wave][q]; float w = wbuf[wave][q];
      uint hv = act ? *(const uint*)(h2p + (size_t)s*68) : 0u;
      den  += w;
      acc0 += w * bf2f((ushort)(hv & 0xffff));
      acc1 += w * bf2f((ushort)(hv >> 16));
    }
  }
  if (!act) return;
  float idn = 1.f / (den + 1e-16f);
  int i = tr;
  int c1 = c0 + 1;
  float v0 = acc0*idn + gb2[c0];
  if (c0 < 3) out[NT*64 + dd*3 + c0] = pos[i*3 + c0] + v0;
  else        out[dd*64 + (c0-3)]    = x[i*64 + (c0-3)] + v0;
  if (c1 < 67){
    float v1 = acc1*idn + gb2[c1];
    if (c1 < 3) out[NT*64 + dd*3 + c1] = pos[i*3 + c1] + v1;
    else        out[dd*64 + (c1-3)]    = x[i*64 + (c1-3)] + v1;
  }
}

extern "C" void kernel_launch(void* const* d_in, const int* in_sizes, int n_in,
                              void* d_out, int out_size, void* d_ws, size_t ws_size,
                              hipStream_t stream){
  const float* z    = (const float*)d_in[0];
  const float* x    = (const float*)d_in[1];
  const float* pos  = (const float*)d_in[2];
  const int*   eidx = (const int*)  d_in[3];
  const float* w1   = (const float*)d_in[4];
  const float* b1   = (const float*)d_in[5];
  const float* w2   = (const float*)d_in[6];
  const float* b2   = (const float*)d_in[7];
  const float* w3   = (const float*)d_in[8];
  const float* b3   = (const float*)d_in[9];
  const float* gw0  = (const float*)d_in[10];
  const float* ga0s = (const float*)d_in[11];
  const float* ga0d = (const float*)d_in[12];
  const float* gb0  = (const float*)d_in[13];
  const float* gw1  = (const float*)d_in[14];
  const float* ga1s = (const float*)d_in[15];
  const float* ga1d = (const float*)d_in[16];
  const float* gb1  = (const float*)d_in[17];
  const float* gw2  = (const float*)d_in[18];
  const float* ga2s = (const float*)d_in[19];
  const float* ga2d = (const float*)d_in[20];
  const float* gb2  = (const float*)d_in[21];
  const float* ln0g = (const float*)d_in[22];
  const float* ln0b = (const float*)d_in[23];
  const float* ln1g = (const float*)d_in[24];
  const float* ln1b = (const float*)d_in[25];
  float* out = (float*)d_out;

  float* ws       = (float*)d_ws;
  float* styleW0  = ws;                  // 256
  float* s1buf    = ws + 256;            // 512
  float* s2buf    = s1buf + 512;         // 1024
  float* stbuf    = s2buf + 1024;        // 256
  float* alS      = stbuf + 256;         // 80000
  float* alD      = alS + 80000;         // 80000
  ushort* htA     = (ushort*)(alD + 80000);  // NT*128 bf16
  ushort* htB     = htA + (size_t)NT*128;    // NT*128 bf16
  ushort* ht2c    = htB + (size_t)NT*128;    // NT*68 bf16
  int*   cnt      = (int*)(ht2c + (size_t)NT*68); // Nn
  int*   cursor   = cnt + Nn;                // Nn
  int*   row_start= cursor + Nn;             // Nn+1
  ushort* csr     = (ushort*)(row_start + Nn + 1);  // Me (ushort)

  // style path: z[2,128] -> s1[2,256] -> s2[2,512] -> style[2,128] -> styleW0[2,128]
  k_mlp<128><<<(2*256+3)/4, 256, 0, stream>>>(z,     w1, b1, s1buf, 256, 1);
  k_mlp<256><<<(2*512+3)/4, 256, 0, stream>>>(s1buf, w2, b2, s2buf, 512, 1);
  k_mlp<512><<<(2*128+3)/4, 256, 0, stream>>>(s2buf, w3, b3, stbuf, 128, 0);
  k_mlp<128><<<(2*128+3)/4, 256, 0, stream>>>(stbuf, gw0 + 64*128, (const float*)nullptr, styleW0, 128, 0);

  // CSR by dst (template graph only; ushort entries)
  k_zero<<<(Nn+255)/256, 256, 0, stream>>>(cnt, Nn);
  k_hist<<<(Me+255)/256, 256, 0, stream>>>(eidx, cnt);
  k_scan<<<1, 1024, 0, stream>>>(cnt, row_start, cursor);
  k_scatter<<<(Me+255)/256, 256, 0, stream>>>(eidx, cursor, csr);

  const int MB = (NT+127)/128;
  // layer 0 (ht0 + fused layer-0 logits)
  k_ht0<<<(Nn+31)/32, 256, 0, stream>>>(x, gw0, styleW0, ga0s, ga0d, htA, alS, alD);
  k_gat128<<<(NT+3)/4, 256, 0, stream>>>(htA, alS, alD, row_start, csr,
                                         gb0, ln0g, ln0b, htB, NT);
  // layer 1 (matmul + fused logits)
  k_mm_mfma<128,128,8,4><<<MB, 256, 0, stream>>>(htB, gw1, htA, ga1s, ga1d, alS, alD, NT);
  k_gat128<<<(NT+3)/4, 256, 0, stream>>>(htA, alS, alD, row_start, csr,
                                         gb1, ln1g, ln1b, htB, NT);
  // layer 2 (matmul + fused logits, 1 head; then fused residual + final write)
  k_mm_mfma<67,68,5,1><<<MB, 256, 0, stream>>>(htB, gw2, ht2c, ga2s, ga2d, alS, alD, NT);
  k_gat_out<<<(NT+3)/4, 256, 0, stream>>>(ht2c, alS, alD, row_start, csr,
                                          gb2, x, pos, out, NT);
}

// Round 10
// 157.428 us; speedup vs baseline: 1.1877x; 1.1877x over previous
//
#include <hip/hip_runtime.h>
#include <hip/hip_bf16.h>

#define DEV_INLINE __device__ __forceinline__

constexpr int Nn   = 10000;     // nodes per batch
constexpr int NT   = 20000;     // B*N
constexpr int Me   = 320000;    // template edges
constexpr int STRIDE = 96;      // padded CSR slot stride (max in-degree ~60)
constexpr float NEG = 0.2f;

typedef float  f32x4  __attribute__((ext_vector_type(4)));
typedef short  bf16x8 __attribute__((ext_vector_type(8)));

DEV_INLINE float leaky(float x){ return x >= 0.f ? x : NEG*x; }

DEV_INLINE ushort f2bf(float v){
  __hip_bfloat16 h = __float2bfloat16(v);
  return *reinterpret_cast<ushort*>(&h);
}
DEV_INLINE float bf2f(ushort u){
  uint x = ((uint)u) << 16;
  return __uint_as_float(x);
}
DEV_INLINE float sel4(float4 w, int h){
  return h < 2 ? (h == 0 ? w.x : w.y) : (h == 2 ? w.z : w.w);
}
DEV_INLINE float red16(float v){
  v += __shfl_xor(v, 1); v += __shfl_xor(v, 2);
  v += __shfl_xor(v, 4); v += __shfl_xor(v, 8);
  return v;
}
DEV_INLINE float red32(float v){
  v += __shfl_xor(v, 1); v += __shfl_xor(v, 2);
  v += __shfl_xor(v, 4); v += __shfl_xor(v, 8);
  v += __shfl_xor(v, 16);
  return v;
}

// ---------------- generic small MLP stage: out[2*OD] = act(in[2,K] @ W[K,OD] + b) ----------------
// blocks >= mlpBlocks zero the cnt buffer (fused utility work).
template<int K>
__global__ __launch_bounds__(256) void k_mlp(const float* __restrict__ in,
    const float* __restrict__ W, const float* __restrict__ bias,
    float* __restrict__ out, int OD, int doAct, int mlpBlocks,
    int* __restrict__ zbuf, int zn){
  if ((int)blockIdx.x >= mlpBlocks){
    int i = (blockIdx.x - mlpBlocks)*256 + threadIdx.x;
    if (i < zn) zbuf[i] = 0;
    return;
  }
  int wave = threadIdx.x >> 6, lane = threadIdx.x & 63;
  int o = blockIdx.x*4 + wave;
  if (o >= 2*OD) return;
  int b = (o >= OD) ? 1 : 0;
  int j = o - b*OD;
  const float* __restrict__ ip = in + b*K;
  float acc = 0.f;
  #pragma unroll 2
  for (int k = lane; k < K; k += 64) acc += ip[k] * W[(size_t)k*OD + j];
  #pragma unroll
  for (int off = 32; off; off >>= 1) acc += __shfl_xor(acc, off);
  if (lane == 0){
    float v = acc + (bias ? bias[j] : 0.f);
    out[o] = doAct ? leaky(v) : v;
  }
}

// ---------------- ht0(bf16) = x @ gw0[:64,:] + styleW0[b], fused layer-0 logits ----------------
__global__ __launch_bounds__(256) void k_ht0(const float* __restrict__ x,
    const float* __restrict__ gw0, const float* __restrict__ styleW0,
    const float* __restrict__ a_s, const float* __restrict__ a_d,
    ushort* __restrict__ ht0, float* __restrict__ alS, float* __restrict__ alD){
  __shared__ float wl[64][128];
  __shared__ float xl[32][64];
  __shared__ float sw[2][128];
  __shared__ float stycS[2][4], stycD[2][4];
  int t = threadIdx.x;
  for (int i=t; i<64*128; i+=256) wl[i>>7][i&127] = gw0[i];
  if (t < 256) sw[t>>7][t&127] = styleW0[t];
  int row0 = blockIdx.x*32;
  for (int i=t; i<32*64; i+=256){
    int r = i>>6, c = i&63; int gr = row0 + r;
    xl[r][c] = (gr < Nn) ? x[gr*64 + c] : 0.f;
  }
  __syncthreads();
  int c = t & 127, rh = t >> 7, lane = t & 63;
  float as_c = a_s[c], ad_c = a_d[c];
  int h = c >> 5;

  // style-const logits per (batch, head)
  if (t < 128){
    float v0s = sw[0][c]*as_c, v0d = sw[0][c]*ad_c;
    float v1s = sw[1][c]*as_c, v1d = sw[1][c]*ad_c;
    v0s = red32(v0s); v0d = red32(v0d);
    v1s = red32(v1s); v1d = red32(v1d);
    if ((lane & 31) == 0){
      stycS[0][h] = v0s; stycD[0][h] = v0d;
      stycS[1][h] = v1s; stycD[1][h] = v1d;
    }
  }

  float acc[16];
  #pragma unroll
  for (int i=0;i<16;i++) acc[i]=0.f;
  for (int k=0;k<64;k++){
    float w = wl[k][c];
    #pragma unroll
    for (int i=0;i<16;i++) acc[i] += xl[rh+2*i][k]*w;
  }
  __syncthreads();   // stycS/stycD visible
  float s0 = sw[0][c], s1 = sw[1][c];
  #pragma unroll
  for (int i=0;i<16;i++){
    int gr = row0 + rh + 2*i;
    if (gr < Nn){
      ht0[(size_t)gr*128 + c]      = f2bf(acc[i] + s0);
      ht0[(size_t)(Nn+gr)*128 + c] = f2bf(acc[i] + s1);
    }
    float vs = acc[i]*as_c, vd = acc[i]*ad_c;
    vs = red32(vs); vd = red32(vd);
    if ((lane & 31) == 0 && gr < Nn){
      alS[(size_t)gr*4 + h]      = vs + stycS[0][h];
      alD[(size_t)gr*4 + h]      = vd + stycD[0][h];
      alS[(size_t)(Nn+gr)*4 + h] = vs + stycS[1][h];
      alD[(size_t)(Nn+gr)*4 + h] = vd + stycD[1][h];
    }
  }
}

// ---- MFMA matmul + fused attention logits ----
template<int NCOL, int LDO, int NF, int NHEAD>
__global__ __launch_bounds__(256) void k_mm_mfma(const ushort* __restrict__ A,
    const float* __restrict__ W, ushort* __restrict__ out,
    const float* __restrict__ a_s, const float* __restrict__ a_d,
    float* __restrict__ alS, float* __restrict__ alD, int M){
  constexpr int NCOLP = NF*16;
  __shared__ ushort bt[NCOLP*128];  // Bt[c][k], XOR-swizzled
  int t = threadIdx.x;
  int wid = t >> 6, lane = t & 63, l15 = lane & 15, g = lane >> 4;
  int mbase = blockIdx.x*128 + wid*32;

  bf16x8 afr[2][4];
  #pragma unroll
  for (int mf=0; mf<2; mf++){
    int row = mbase + mf*16 + l15;
    int rc = row < M ? row : M-1;
    const ushort* ap = A + (size_t)rc*128 + g*8;
    #pragma unroll
    for (int ks=0; ks<4; ks++)
      afr[mf][ks] = *(const bf16x8*)(ap + ks*32);
  }

  for (int idx = t; idx < 128*NCOLP; idx += 256){
    int k = idx / NCOLP, c = idx % NCOLP;
    float v = (c < NCOL) ? W[k*NCOL + c] : 0.f;
    uint byte = ((uint)(c*128 + k) << 1) ^ ((uint)(c&7) << 4);
    *(ushort*)((char*)bt + byte) = f2bf(v);
  }
  __syncthreads();

  f32x4 acc[2][NF];
  #pragma unroll
  for (int mf=0; mf<2; mf++)
    #pragma unroll
    for (int nf=0; nf<NF; nf++) acc[mf][nf] = (f32x4){0.f,0.f,0.f,0.f};

  #pragma unroll
  for (int ks=0; ks<4; ks++){
    int kb = ks*32 + g*8;
    bf16x8 bfr[NF];
    #pragma unroll
    for (int nf=0; nf<NF; nf++){
      int c = nf*16 + l15;
      uint byte = ((uint)(c*128 + kb) << 1) ^ ((uint)(c&7) << 4);
      bfr[nf] = *(const bf16x8*)((const char*)bt + byte);
    }
    #pragma unroll
    for (int mf=0; mf<2; mf++)
      #pragma unroll
      for (int nf=0; nf<NF; nf++)
        acc[mf][nf] = __builtin_amdgcn_mfma_f32_16x16x32_bf16(
            afr[mf][ks], bfr[nf], acc[mf][nf], 0, 0, 0);
  }

  // C/D layout: col = lane&15, row = (lane>>4)*4 + r
  #pragma unroll
  for (int mf=0; mf<2; mf++){
    int rbase = mbase + mf*16 + g*4;
    #pragma unroll
    for (int nf=0; nf<NF; nf++){
      int c = nf*16 + l15;
      if (c < LDO){
        #pragma unroll
        for (int r=0; r<4; r++){
          int row = rbase + r;
          if (row < M) out[(size_t)row*LDO + c] = (c < NCOL) ? f2bf(acc[mf][nf][r]) : (ushort)0;
        }
      }
    }
  }

  // fused per-row attention logits
  float as_v[NF], ad_v[NF];
  #pragma unroll
  for (int nf=0; nf<NF; nf++){
    int c = nf*16 + l15;
    as_v[nf] = (c < NCOL) ? a_s[c] : 0.f;
    ad_v[nf] = (c < NCOL) ? a_d[c] : 0.f;
  }
  #pragma unroll
  for (int mf=0; mf<2; mf++){
    #pragma unroll
    for (int r=0; r<4; r++){
      int row = mbase + mf*16 + g*4 + r;
      if (NHEAD == 4){
        float ps0 = acc[mf][0][r]*as_v[0] + acc[mf][1][r]*as_v[1];
        float ps1 = acc[mf][2][r]*as_v[2] + acc[mf][3][r]*as_v[3];
        float ps2 = acc[mf][4][r]*as_v[4] + acc[mf][5][r]*as_v[5];
        float ps3 = acc[mf][6][r]*as_v[6] + acc[mf][7][r]*as_v[7];
        float pd0 = acc[mf][0][r]*ad_v[0] + acc[mf][1][r]*ad_v[1];
        float pd1 = acc[mf][2][r]*ad_v[2] + acc[mf][3][r]*ad_v[3];
        float pd2 = acc[mf][4][r]*ad_v[4] + acc[mf][5][r]*ad_v[5];
        float pd3 = acc[mf][6][r]*ad_v[6] + acc[mf][7][r]*ad_v[7];
        ps0 = red16(ps0); ps1 = red16(ps1); ps2 = red16(ps2); ps3 = red16(ps3);
        pd0 = red16(pd0); pd1 = red16(pd1); pd2 = red16(pd2); pd3 = red16(pd3);
        if (l15 == 0 && row < M){
          *(float4*)(alS + (size_t)row*4) = make_float4(ps0, ps1, ps2, ps3);
          *(float4*)(alD + (size_t)row*4) = make_float4(pd0, pd1, pd2, pd3);
        }
      } else {
        float ps = 0.f, pd = 0.f;
        #pragma unroll
        for (int nf=0; nf<NF; nf++){
          ps += acc[mf][nf][r]*as_v[nf];
          pd += acc[mf][nf][r]*ad_v[nf];
        }
        ps = red16(ps); pd = red16(pd);
        if (l15 == 0 && row < M){
          alS[row] = ps; alD[row] = pd;
        }
      }
    }
  }
}

// ---------------- padded-slot CSR build (single pass; cnt doubles as degree) ----------------
__global__ void k_scatter(const int* __restrict__ eidx,
    int* __restrict__ cnt, ushort* __restrict__ slot){
  int e = blockIdx.x*256 + threadIdx.x;
  if (e >= Me) return;
  int s = eidx[e], d = eidx[Me + e];
  int p = atomicAdd(&cnt[d], 1);
  if (p < STRIDE) slot[(size_t)d*STRIDE + p] = (ushort)s;
}

// ---------------- GAT aggregation layer 0/1, bf16 gathers, paired cols ----------------
__global__ __launch_bounds__(256) void k_gat128(const ushort* __restrict__ ht,
    const float* __restrict__ alS, const float* __restrict__ alD,
    const int* __restrict__ deg, const ushort* __restrict__ slot,
    const float* __restrict__ gb, const float* __restrict__ lng,
    const float* __restrict__ lnb, ushort* __restrict__ outH, int n){
  __shared__ float4 wbuf[4][64];
  __shared__ int    sbuf[4][64];
  int wave = threadIdx.x >> 6, lane = threadIdx.x & 63;
  int dd = blockIdx.x*4 + wave;
  if (dd >= n) return;
  int tr  = (dd >= Nn) ? dd - Nn : dd;
  int off = (dd >= Nn) ? Nn : 0;
  int c0 = lane*2;
  int h  = lane >> 4;
  float4 ald4 = *(const float4*)(alD + dd*4);
  int dg = deg[tr]; if (dg > STRIDE) dg = STRIDE;
  int begin = tr*STRIDE, end = begin + dg;

  // self-loop term
  float4 asl = *(const float4*)(alS + dd*4);
  float4 wsl;
  wsl.x = __expf(leaky(asl.x + ald4.x));
  wsl.y = __expf(leaky(asl.y + ald4.y));
  wsl.z = __expf(leaky(asl.z + ald4.z));
  wsl.w = __expf(leaky(asl.w + ald4.w));
  float es = sel4(wsl, h);
  uint sv0 = *(const uint*)(ht + (size_t)dd*128 + c0);
  float den  = es;
  float acc0 = es * bf2f((ushort)(sv0 & 0xffff));
  float acc1 = es * bf2f((ushort)(sv0 >> 16));

  const ushort* __restrict__ htp = ht + c0;

  for (int j = begin; j < end; j += 64){
    int nc = min(64, end - j);
    // phase A: one edge per lane -> 4-head weights into wave-private LDS
    if (lane < nc){
      int s = (int)slot[j + lane] + off;
      float4 as4 = *(const float4*)(alS + s*4);
      float4 w;
      w.x = __expf(leaky(as4.x + ald4.x));
      w.y = __expf(leaky(as4.y + ald4.y));
      w.z = __expf(leaky(as4.z + ald4.z));
      w.w = __expf(leaky(as4.w + ald4.w));
      wbuf[wave][lane] = w;
      sbuf[wave][lane] = s;
    }
    // phase B: column-parallel FMA (LDS reads broadcast)
    int q = 0;
    for (; q + 8 <= nc; q += 8){
      int sv[8]; float4 wv[8];
      #pragma unroll
      for (int u=0;u<8;u++){ sv[u] = sbuf[wave][q+u]; wv[u] = wbuf[wave][q+u]; }
      uint hv[8];
      #pragma unroll
      for (int u=0;u<8;u++) hv[u] = *(const uint*)(htp + (size_t)sv[u]*128);
      #pragma unroll
      for (int u=0;u<8;u++){
        float e = sel4(wv[u], h);
        den  += e;
        acc0 += e * bf2f((ushort)(hv[u] & 0xffff));
        acc1 += e * bf2f((ushort)(hv[u] >> 16));
      }
    }
    for (; q < nc; q++){
      int s = sbuf[wave][q];
      float e = sel4(wbuf[wave][q], h);
      uint hv = *(const uint*)(htp + (size_t)s*128);
      den  += e;
      acc0 += e * bf2f((ushort)(hv & 0xffff));
      acc1 += e * bf2f((ushort)(hv >> 16));
    }
  }
  float idn = 1.f / (den + 1e-16f);
  float v0 = acc0*idn + gb[c0];
  float v1 = acc1*idn + gb[c0+1];

  // LayerNorm over 128 features held by this wave (2 per lane)
  float sum = v0 + v1, sq = v0*v0 + v1*v1;
  #pragma unroll
  for (int offx = 32; offx; offx >>= 1){
    sum += __shfl_xor(sum, offx);
    sq  += __shfl_xor(sq,  offx);
  }
  float mu  = sum * (1.f/128.f);
  float var = sq  * (1.f/128.f) - mu*mu;
  float inv = rsqrtf(var + 1e-5f);
  float y0 = (v0 - mu)*inv*lng[c0]   + lnb[c0];
  float y1 = (v1 - mu)*inv*lng[c0+1] + lnb[c0+1];
  uint ow = (uint)f2bf(leaky(y0)) | ((uint)f2bf(leaky(y1)) << 16);
  *(uint*)(outH + (size_t)dd*128 + c0) = ow;
}

// ---------------- GAT output layer (1 head, 67 cols), bf16 gathers + residual ----------------
__global__ __launch_bounds__(256) void k_gat_out(const ushort* __restrict__ ht2,
    const float* __restrict__ alS, const float* __restrict__ alD,
    const int* __restrict__ deg, const ushort* __restrict__ slot,
    const float* __restrict__ gb2, const float* __restrict__ x,
    const float* __restrict__ pos, float* __restrict__ out, int n){
  __shared__ float wbuf[4][64];
  __shared__ int   sbuf[4][64];
  int wave = threadIdx.x >> 6, lane = threadIdx.x & 63;
  int dd = blockIdx.x*4 + wave;
  if (dd >= n) return;
  int tr  = (dd >= Nn) ? dd - Nn : dd;
  int off = (dd >= Nn) ? Nn : 0;
  int c0 = lane*2;
  bool act = (c0 < 67);             // lane < 34
  float ald = alD[dd];
  int dg = deg[tr]; if (dg > STRIDE) dg = STRIDE;
  int begin = tr*STRIDE, end = begin + dg;

  // self-loop term
  float wsl = __expf(leaky(alS[dd] + ald));
  float den  = wsl;
  uint sv0 = act ? *(const uint*)(ht2 + (size_t)dd*68 + c0) : 0u;
  float acc0 = wsl * bf2f((ushort)(sv0 & 0xffff));
  float acc1 = wsl * bf2f((ushort)(sv0 >> 16));

  const ushort* __restrict__ h2p = ht2 + c0;

  for (int j = begin; j < end; j += 64){
    int nc = min(64, end - j);
    if (lane < nc){
      int s = (int)slot[j + lane] + off;
      wbuf[wave][lane] = __expf(leaky(alS[s] + ald));
      sbuf[wave][lane] = s;
    }
    int q = 0;
    for (; q + 8 <= nc; q += 8){
      int sv[8]; float wv[8];
      #pragma unroll
      for (int u=0;u<8;u++){ sv[u] = sbuf[wave][q+u]; wv[u] = wbuf[wave][q+u]; }
      uint hv[8];
      #pragma unroll
      for (int u=0;u<8;u++) hv[u] = act ? *(const uint*)(h2p + (size_t)sv[u]*68) : 0u;
      #pragma unroll
      for (int u=0;u<8;u++){
        den  += wv[u];
        acc0 += wv[u] * bf2f((ushort)(hv[u] & 0xffff));
        acc1 += wv[u] * bf2f((ushort)(hv[u] >> 16));
      }
    }
    for (; q < nc; q++){
      int s = sbuf[wave][q]; float w = wbuf[wave][q];
      uint hv = act ? *(const uint*)(h2p + (size_t)s*68) : 0u;
      den  += w;
      acc0 += w * bf2f((ushort)(hv & 0xffff));
      acc1 += w * bf2f((ushort)(hv >> 16));
    }
  }
  if (!act) return;
  float idn = 1.f / (den + 1e-16f);
  int i = tr;
  int c1 = c0 + 1;
  float v0 = acc0*idn + gb2[c0];
  if (c0 < 3) out[NT*64 + dd*3 + c0] = pos[i*3 + c0] + v0;
  else        out[dd*64 + (c0-3)]    = x[i*64 + (c0-3)] + v0;
  if (c1 < 67){
    float v1 = acc1*idn + gb2[c1];
    if (c1 < 3) out[NT*64 + dd*3 + c1] = pos[i*3 + c1] + v1;
    else        out[dd*64 + (c1-3)]    = x[i*64 + (c1-3)] + v1;
  }
}

extern "C" void kernel_launch(void* const* d_in, const int* in_sizes, int n_in,
                              void* d_out, int out_size, void* d_ws, size_t ws_size,
                              hipStream_t stream){
  const float* z    = (const float*)d_in[0];
  const float* x    = (const float*)d_in[1];
  const float* pos  = (const float*)d_in[2];
  const int*   eidx = (const int*)  d_in[3];
  const float* w1   = (const float*)d_in[4];
  const float* b1   = (const float*)d_in[5];
  const float* w2   = (const float*)d_in[6];
  const float* b2   = (const float*)d_in[7];
  const float* w3   = (const float*)d_in[8];
  const float* b3   = (const float*)d_in[9];
  const float* gw0  = (const float*)d_in[10];
  const float* ga0s = (const float*)d_in[11];
  const float* ga0d = (const float*)d_in[12];
  const float* gb0  = (const float*)d_in[13];
  const float* gw1  = (const float*)d_in[14];
  const float* ga1s = (const float*)d_in[15];
  const float* ga1d = (const float*)d_in[16];
  const float* gb1  = (const float*)d_in[17];
  const float* gw2  = (const float*)d_in[18];
  const float* ga2s = (const float*)d_in[19];
  const float* ga2d = (const float*)d_in[20];
  const float* gb2  = (const float*)d_in[21];
  const float* ln0g = (const float*)d_in[22];
  const float* ln0b = (const float*)d_in[23];
  const float* ln1g = (const float*)d_in[24];
  const float* ln1b = (const float*)d_in[25];
  float* out = (float*)d_out;

  float* ws       = (float*)d_ws;
  float* styleW0  = ws;                  // 256
  float* s1buf    = ws + 256;            // 512
  float* s2buf    = s1buf + 512;         // 1024
  float* stbuf    = s2buf + 1024;        // 256
  float* alS      = stbuf + 256;         // 80000
  float* alD      = alS + 80000;         // 80000
  ushort* htA     = (ushort*)(alD + 80000);  // NT*128 bf16
  ushort* htB     = htA + (size_t)NT*128;    // NT*128 bf16
  ushort* ht2c    = htB + (size_t)NT*128;    // NT*68 bf16
  int*   cnt      = (int*)(ht2c + (size_t)NT*68); // Nn (degree)
  ushort* slot    = (ushort*)(cnt + Nn);          // Nn*STRIDE (padded CSR)

  // style path; first dispatch also zeroes cnt via extra blocks
  const int ZB = (Nn + 255)/256;   // 40 zero-blocks
  k_mlp<128><<<128 + ZB, 256, 0, stream>>>(z,     w1, b1, s1buf, 256, 1, 128, cnt, Nn);
  k_mlp<256><<<256,      256, 0, stream>>>(s1buf, w2, b2, s2buf, 512, 1, 256, nullptr, 0);
  k_mlp<512><<<64,       256, 0, stream>>>(s2buf, w3, b3, stbuf, 128, 0, 64, nullptr, 0);
  k_mlp<128><<<64,       256, 0, stream>>>(stbuf, gw0 + 64*128, (const float*)nullptr, styleW0, 128, 0, 64, nullptr, 0);

  // padded-slot CSR (single pass)
  k_scatter<<<(Me+255)/256, 256, 0, stream>>>(eidx, cnt, slot);

  const int MB = (NT+127)/128;
  // layer 0 (ht0 + fused layer-0 logits)
  k_ht0<<<(Nn+31)/32, 256, 0, stream>>>(x, gw0, styleW0, ga0s, ga0d, htA, alS, alD);
  k_gat128<<<(NT+3)/4, 256, 0, stream>>>(htA, alS, alD, cnt, slot,
                                         gb0, ln0g, ln0b, htB, NT);
  // layer 1 (matmul + fused logits)
  k_mm_mfma<128,128,8,4><<<MB, 256, 0, stream>>>(htB, gw1, htA, ga1s, ga1d, alS, alD, NT);
  k_gat128<<<(NT+3)/4, 256, 0, stream>>>(htA, alS, alD, cnt, slot,
                                         gb1, ln1g, ln1b, htB, NT);
  // layer 2 (matmul + fused logits, 1 head; then fused residual + final write)
  k_mm_mfma<67,68,5,1><<<MB, 256, 0, stream>>>(htB, gw2, ht2c, ga2s, ga2d, alS, alD, NT);
  k_gat_out<<<(NT+3)/4, 256, 0, stream>>>(ht2c, alS, alD, cnt, slot,
                                          gb2, x, pos, out, NT);
}

// Round 11
// 136.683 us; speedup vs baseline: 1.3679x; 1.1518x over previous
//
#include <hip/hip_runtime.h>
#include <hip/hip_bf16.h>

#define DEV_INLINE __device__ __forceinline__

constexpr int Nn   = 10000;     // nodes per batch
constexpr int NT   = 20000;     // B*N
constexpr int Me   = 320000;    // template edges
constexpr int STRIDE = 96;      // padded CSR slot stride (max in-degree ~60)
constexpr float NEG = 0.2f;

typedef float  f32x4  __attribute__((ext_vector_type(4)));
typedef short  bf16x8 __attribute__((ext_vector_type(8)));

DEV_INLINE float leaky(float x){ return x >= 0.f ? x : NEG*x; }

DEV_INLINE ushort f2bf(float v){
  __hip_bfloat16 h = __float2bfloat16(v);
  return *reinterpret_cast<ushort*>(&h);
}
DEV_INLINE float bf2f(ushort u){
  uint x = ((uint)u) << 16;
  return __uint_as_float(x);
}
DEV_INLINE float sel4(float4 w, int h){
  return h < 2 ? (h == 0 ? w.x : w.y) : (h == 2 ? w.z : w.w);
}
DEV_INLINE float red16(float v){
  v += __shfl_xor(v, 1); v += __shfl_xor(v, 2);
  v += __shfl_xor(v, 4); v += __shfl_xor(v, 8);
  return v;
}
DEV_INLINE float red32(float v){
  v += __shfl_xor(v, 1); v += __shfl_xor(v, 2);
  v += __shfl_xor(v, 4); v += __shfl_xor(v, 8);
  v += __shfl_xor(v, 16);
  return v;
}

// ---------------- generic small MLP stage + fused utility tail-blocks ----------------
// blocks >= mlpBlocks: first zblk blocks zero zbuf, the rest convert xsrc(f32)->xdst(bf16).
template<int K>
__global__ __launch_bounds__(256) void k_mlp(const float* __restrict__ in,
    const float* __restrict__ W, const float* __restrict__ bias,
    float* __restrict__ out, int OD, int doAct, int mlpBlocks,
    int* __restrict__ zbuf, int zn, int zblk,
    const float* __restrict__ xsrc, ushort* __restrict__ xdst, int xn4){
  if ((int)blockIdx.x >= mlpBlocks){
    int b2 = blockIdx.x - mlpBlocks;
    if (b2 < zblk){
      int i = b2*256 + threadIdx.x;
      if (i < zn) zbuf[i] = 0;
    } else {
      int i4 = (b2 - zblk)*256 + threadIdx.x;
      if (i4 < xn4){
        float4 v = ((const float4*)xsrc)[i4];
        ushort4 o;
        o.x = f2bf(v.x); o.y = f2bf(v.y); o.z = f2bf(v.z); o.w = f2bf(v.w);
        ((ushort4*)xdst)[i4] = o;
      }
    }
    return;
  }
  int wave = threadIdx.x >> 6, lane = threadIdx.x & 63;
  int o = blockIdx.x*4 + wave;
  if (o >= 2*OD) return;
  int b = (o >= OD) ? 1 : 0;
  int j = o - b*OD;
  const float* __restrict__ ip = in + b*K;
  float acc = 0.f;
  #pragma unroll 2
  for (int k = lane; k < K; k += 64) acc += ip[k] * W[(size_t)k*OD + j];
  #pragma unroll
  for (int off = 32; off; off >>= 1) acc += __shfl_xor(acc, off);
  if (lane == 0){
    float v = acc + (bias ? bias[j] : 0.f);
    out[o] = doAct ? leaky(v) : v;
  }
}

// ---- MFMA ht0: ht0[b,row,c](bf16) = x_bf16[row,:64] @ gw0[:64,c] + styleW0[b,c],
//      fused layer-0 logits; blocks >= mbBlocks do the CSR scatter instead. ----
__global__ __launch_bounds__(256) void k_ht0_mfma(const ushort* __restrict__ xb,
    const float* __restrict__ gw0, const float* __restrict__ styleW0,
    const float* __restrict__ a_s, const float* __restrict__ a_d,
    ushort* __restrict__ ht0, float* __restrict__ alS, float* __restrict__ alD,
    int mbBlocks, const int* __restrict__ eidx, int* __restrict__ cnt,
    ushort* __restrict__ slot){
  if ((int)blockIdx.x >= mbBlocks){
    int e = (blockIdx.x - mbBlocks)*256 + threadIdx.x;
    if (e < Me){
      int s = eidx[e], d = eidx[Me + e];
      int p = atomicAdd(&cnt[d], 1);
      if (p < STRIDE) slot[(size_t)d*STRIDE + p] = (ushort)s;
    }
    return;
  }
  __shared__ ushort bt[128*64];           // Bt[c][k], XOR-swizzled
  __shared__ float stycS[2][4], stycD[2][4];
  int t = threadIdx.x;
  int wid = t >> 6, lane = t & 63, l15 = lane & 15, g = lane >> 4;
  int mbase = blockIdx.x*128 + wid*32;

  // A fragments: rows of x_bf16 (K=64 -> 2 k-steps)
  bf16x8 afr[2][2];
  #pragma unroll
  for (int mf=0; mf<2; mf++){
    int row = mbase + mf*16 + l15;
    int rc = row < Nn ? row : Nn-1;
    const ushort* ap = xb + (size_t)rc*64 + g*8;
    #pragma unroll
    for (int ks=0; ks<2; ks++)
      afr[mf][ks] = *(const bf16x8*)(ap + ks*32);
  }

  // stage gw0[:64,:] -> LDS transposed bf16, swizzled
  for (int idx = t; idx < 64*128; idx += 256){
    int k = idx >> 7, c = idx & 127;
    uint byte = ((uint)(c*64 + k) << 1) ^ ((uint)(c&7) << 4);
    *(ushort*)((char*)bt + byte) = f2bf(gw0[k*128 + c]);
  }

  // style-const logits per (batch, head): threads t<128 cover c=t
  if (t < 128){
    int c = t, h = c >> 5;
    float as_c = a_s[c], ad_c = a_d[c];
    float s0 = styleW0[c], s1 = styleW0[128 + c];
    float v0s = red32(s0*as_c), v0d = red32(s0*ad_c);
    float v1s = red32(s1*as_c), v1d = red32(s1*ad_c);
    if ((lane & 31) == 0){
      stycS[0][h] = v0s; stycD[0][h] = v0d;
      stycS[1][h] = v1s; stycD[1][h] = v1d;
    }
  }
  __syncthreads();

  f32x4 acc[2][8];
  #pragma unroll
  for (int mf=0; mf<2; mf++)
    #pragma unroll
    for (int nf=0; nf<8; nf++) acc[mf][nf] = (f32x4){0.f,0.f,0.f,0.f};

  #pragma unroll
  for (int ks=0; ks<2; ks++){
    int kb = ks*32 + g*8;
    bf16x8 bfr[8];
    #pragma unroll
    for (int nf=0; nf<8; nf++){
      int c = nf*16 + l15;
      uint byte = ((uint)(c*64 + kb) << 1) ^ ((uint)(c&7) << 4);
      bfr[nf] = *(const bf16x8*)((const char*)bt + byte);
    }
    #pragma unroll
    for (int mf=0; mf<2; mf++)
      #pragma unroll
      for (int nf=0; nf<8; nf++)
        acc[mf][nf] = __builtin_amdgcn_mfma_f32_16x16x32_bf16(
            afr[mf][ks], bfr[nf], acc[mf][nf], 0, 0, 0);
  }

  // epilogue: dual-batch store + fused logits
  float sw0[8], sw1[8], as_v[8], ad_v[8];
  #pragma unroll
  for (int nf=0; nf<8; nf++){
    int c = nf*16 + l15;
    sw0[nf] = styleW0[c]; sw1[nf] = styleW0[128 + c];
    as_v[nf] = a_s[c];    ad_v[nf] = a_d[c];
  }
  #pragma unroll
  for (int mf=0; mf<2; mf++){
    int rbase = mbase + mf*16 + g*4;
    #pragma unroll
    for (int r=0; r<4; r++){
      int row = rbase + r;
      bool ok = (row < Nn);
      #pragma unroll
      for (int nf=0; nf<8; nf++){
        int c = nf*16 + l15;
        if (ok){
          float v = acc[mf][nf][r];
          ht0[(size_t)row*128 + c]      = f2bf(v + sw0[nf]);
          ht0[(size_t)(Nn+row)*128 + c] = f2bf(v + sw1[nf]);
        }
      }
      float ps0 = acc[mf][0][r]*as_v[0] + acc[mf][1][r]*as_v[1];
      float ps1 = acc[mf][2][r]*as_v[2] + acc[mf][3][r]*as_v[3];
      float ps2 = acc[mf][4][r]*as_v[4] + acc[mf][5][r]*as_v[5];
      float ps3 = acc[mf][6][r]*as_v[6] + acc[mf][7][r]*as_v[7];
      float pd0 = acc[mf][0][r]*ad_v[0] + acc[mf][1][r]*ad_v[1];
      float pd1 = acc[mf][2][r]*ad_v[2] + acc[mf][3][r]*ad_v[3];
      float pd2 = acc[mf][4][r]*ad_v[4] + acc[mf][5][r]*ad_v[5];
      float pd3 = acc[mf][6][r]*ad_v[6] + acc[mf][7][r]*ad_v[7];
      ps0 = red16(ps0); ps1 = red16(ps1); ps2 = red16(ps2); ps3 = red16(ps3);
      pd0 = red16(pd0); pd1 = red16(pd1); pd2 = red16(pd2); pd3 = red16(pd3);
      if (l15 == 0 && ok){
        *(float4*)(alS + (size_t)row*4) = make_float4(
            ps0 + stycS[0][0], ps1 + stycS[0][1], ps2 + stycS[0][2], ps3 + stycS[0][3]);
        *(float4*)(alD + (size_t)row*4) = make_float4(
            pd0 + stycD[0][0], pd1 + stycD[0][1], pd2 + stycD[0][2], pd3 + stycD[0][3]);
        *(float4*)(alS + (size_t)(Nn+row)*4) = make_float4(
            ps0 + stycS[1][0], ps1 + stycS[1][1], ps2 + stycS[1][2], ps3 + stycS[1][3]);
        *(float4*)(alD + (size_t)(Nn+row)*4) = make_float4(
            pd0 + stycD[1][0], pd1 + stycD[1][1], pd2 + stycD[1][2], pd3 + stycD[1][3]);
      }
    }
  }
}

// ---- MFMA matmul + fused attention logits ----
template<int NCOL, int LDO, int NF, int NHEAD>
__global__ __launch_bounds__(256) void k_mm_mfma(const ushort* __restrict__ A,
    const float* __restrict__ W, ushort* __restrict__ out,
    const float* __restrict__ a_s, const float* __restrict__ a_d,
    float* __restrict__ alS, float* __restrict__ alD, int M){
  constexpr int NCOLP = NF*16;
  __shared__ ushort bt[NCOLP*128];  // Bt[c][k], XOR-swizzled
  int t = threadIdx.x;
  int wid = t >> 6, lane = t & 63, l15 = lane & 15, g = lane >> 4;
  int mbase = blockIdx.x*128 + wid*32;

  bf16x8 afr[2][4];
  #pragma unroll
  for (int mf=0; mf<2; mf++){
    int row = mbase + mf*16 + l15;
    int rc = row < M ? row : M-1;
    const ushort* ap = A + (size_t)rc*128 + g*8;
    #pragma unroll
    for (int ks=0; ks<4; ks++)
      afr[mf][ks] = *(const bf16x8*)(ap + ks*32);
  }

  for (int idx = t; idx < 128*NCOLP; idx += 256){
    int k = idx / NCOLP, c = idx % NCOLP;
    float v = (c < NCOL) ? W[k*NCOL + c] : 0.f;
    uint byte = ((uint)(c*128 + k) << 1) ^ ((uint)(c&7) << 4);
    *(ushort*)((char*)bt + byte) = f2bf(v);
  }
  __syncthreads();

  f32x4 acc[2][NF];
  #pragma unroll
  for (int mf=0; mf<2; mf++)
    #pragma unroll
    for (int nf=0; nf<NF; nf++) acc[mf][nf] = (f32x4){0.f,0.f,0.f,0.f};

  #pragma unroll
  for (int ks=0; ks<4; ks++){
    int kb = ks*32 + g*8;
    bf16x8 bfr[NF];
    #pragma unroll
    for (int nf=0; nf<NF; nf++){
      int c = nf*16 + l15;
      uint byte = ((uint)(c*128 + kb) << 1) ^ ((uint)(c&7) << 4);
      bfr[nf] = *(const bf16x8*)((const char*)bt + byte);
    }
    #pragma unroll
    for (int mf=0; mf<2; mf++)
      #pragma unroll
      for (int nf=0; nf<NF; nf++)
        acc[mf][nf] = __builtin_amdgcn_mfma_f32_16x16x32_bf16(
            afr[mf][ks], bfr[nf], acc[mf][nf], 0, 0, 0);
  }

  // C/D layout: col = lane&15, row = (lane>>4)*4 + r
  #pragma unroll
  for (int mf=0; mf<2; mf++){
    int rbase = mbase + mf*16 + g*4;
    #pragma unroll
    for (int nf=0; nf<NF; nf++){
      int c = nf*16 + l15;
      if (c < LDO){
        #pragma unroll
        for (int r=0; r<4; r++){
          int row = rbase + r;
          if (row < M) out[(size_t)row*LDO + c] = (c < NCOL) ? f2bf(acc[mf][nf][r]) : (ushort)0;
        }
      }
    }
  }

  // fused per-row attention logits
  float as_v[NF], ad_v[NF];
  #pragma unroll
  for (int nf=0; nf<NF; nf++){
    int c = nf*16 + l15;
    as_v[nf] = (c < NCOL) ? a_s[c] : 0.f;
    ad_v[nf] = (c < NCOL) ? a_d[c] : 0.f;
  }
  #pragma unroll
  for (int mf=0; mf<2; mf++){
    #pragma unroll
    for (int r=0; r<4; r++){
      int row = mbase + mf*16 + g*4 + r;
      if (NHEAD == 4){
        float ps0 = acc[mf][0][r]*as_v[0] + acc[mf][1][r]*as_v[1];
        float ps1 = acc[mf][2][r]*as_v[2] + acc[mf][3][r]*as_v[3];
        float ps2 = acc[mf][4][r]*as_v[4] + acc[mf][5][r]*as_v[5];
        float ps3 = acc[mf][6][r]*as_v[6] + acc[mf][7][r]*as_v[7];
        float pd0 = acc[mf][0][r]*ad_v[0] + acc[mf][1][r]*ad_v[1];
        float pd1 = acc[mf][2][r]*ad_v[2] + acc[mf][3][r]*ad_v[3];
        float pd2 = acc[mf][4][r]*ad_v[4] + acc[mf][5][r]*ad_v[5];
        float pd3 = acc[mf][6][r]*ad_v[6] + acc[mf][7][r]*ad_v[7];
        ps0 = red16(ps0); ps1 = red16(ps1); ps2 = red16(ps2); ps3 = red16(ps3);
        pd0 = red16(pd0); pd1 = red16(pd1); pd2 = red16(pd2); pd3 = red16(pd3);
        if (l15 == 0 && row < M){
          *(float4*)(alS + (size_t)row*4) = make_float4(ps0, ps1, ps2, ps3);
          *(float4*)(alD + (size_t)row*4) = make_float4(pd0, pd1, pd2, pd3);
        }
      } else {
        float ps = 0.f, pd = 0.f;
        #pragma unroll
        for (int nf=0; nf<NF; nf++){
          ps += acc[mf][nf][r]*as_v[nf];
          pd += acc[mf][nf][r]*ad_v[nf];
        }
        ps = red16(ps); pd = red16(pd);
        if (l15 == 0 && row < M){
          alS[row] = ps; alD[row] = pd;
        }
      }
    }
  }
}

// ---------------- GAT aggregation layer 0/1, bf16 gathers, paired cols ----------------
__global__ __launch_bounds__(256) void k_gat128(const ushort* __restrict__ ht,
    const float* __restrict__ alS, const float* __restrict__ alD,
    const int* __restrict__ deg, const ushort* __restrict__ slot,
    const float* __restrict__ gb, const float* __restrict__ lng,
    const float* __restrict__ lnb, ushort* __restrict__ outH, int n){
  __shared__ float wbuf[4][4][68];   // [wave][head][edge] padded
  __shared__ int   sbuf[4][64];
  int wave = threadIdx.x >> 6, lane = threadIdx.x & 63;
  int dd = blockIdx.x*4 + wave;
  if (dd >= n) return;
  int tr  = (dd >= Nn) ? dd - Nn : dd;
  int off = (dd >= Nn) ? Nn : 0;
  int c0 = lane*2;
  int h  = lane >> 4;
  float4 ald4 = *(const float4*)(alD + dd*4);
  int dg = deg[tr]; if (dg > STRIDE) dg = STRIDE;
  int begin = tr*STRIDE, end = begin + dg;

  // self-loop term
  float4 asl = *(const float4*)(alS + dd*4);
  float4 wsl;
  wsl.x = __expf(leaky(asl.x + ald4.x));
  wsl.y = __expf(leaky(asl.y + ald4.y));
  wsl.z = __expf(leaky(asl.z + ald4.z));
  wsl.w = __expf(leaky(asl.w + ald4.w));
  float es = sel4(wsl, h);
  uint sv0 = *(const uint*)(ht + (size_t)dd*128 + c0);
  float den  = es;
  float acc0 = es * bf2f((ushort)(sv0 & 0xffff));
  float acc1 = es * bf2f((ushort)(sv0 >> 16));

  const ushort* __restrict__ htp = ht + c0;

  for (int j = begin; j < end; j += 64){
    int nc = min(64, end - j);
    // phase A: one edge per lane -> per-head weight arrays in wave-private LDS
    if (lane < nc){
      int s = (int)slot[j + lane] + off;
      float4 as4 = *(const float4*)(alS + s*4);
      wbuf[wave][0][lane] = __expf(leaky(as4.x + ald4.x));
      wbuf[wave][1][lane] = __expf(leaky(as4.y + ald4.y));
      wbuf[wave][2][lane] = __expf(leaky(as4.z + ald4.z));
      wbuf[wave][3][lane] = __expf(leaky(as4.w + ald4.w));
      sbuf[wave][lane] = s;
    }
    // phase B: column-parallel FMA (scalar LDS broadcasts, no select)
    const float* __restrict__ wh = wbuf[wave][h];
    int q = 0;
    for (; q + 8 <= nc; q += 8){
      int sv[8]; float wv[8];
      #pragma unroll
      for (int u=0;u<8;u++){ sv[u] = sbuf[wave][q+u]; wv[u] = wh[q+u]; }
      uint hv[8];
      #pragma unroll
      for (int u=0;u<8;u++) hv[u] = *(const uint*)(htp + (size_t)sv[u]*128);
      #pragma unroll
      for (int u=0;u<8;u++){
        den  += wv[u];
        acc0 += wv[u] * bf2f((ushort)(hv[u] & 0xffff));
        acc1 += wv[u] * bf2f((ushort)(hv[u] >> 16));
      }
    }
    for (; q < nc; q++){
      int s = sbuf[wave][q];
      float e = wh[q];
      uint hv = *(const uint*)(htp + (size_t)s*128);
      den  += e;
      acc0 += e * bf2f((ushort)(hv & 0xffff));
      acc1 += e * bf2f((ushort)(hv >> 16));
    }
  }
  float idn = 1.f / (den + 1e-16f);
  float v0 = acc0*idn + gb[c0];
  float v1 = acc1*idn + gb[c0+1];

  // LayerNorm over 128 features held by this wave (2 per lane)
  float sum = v0 + v1, sq = v0*v0 + v1*v1;
  #pragma unroll
  for (int offx = 32; offx; offx >>= 1){
    sum += __shfl_xor(sum, offx);
    sq  += __shfl_xor(sq,  offx);
  }
  float mu  = sum * (1.f/128.f);
  float var = sq  * (1.f/128.f) - mu*mu;
  float inv = rsqrtf(var + 1e-5f);
  float y0 = (v0 - mu)*inv*lng[c0]   + lnb[c0];
  float y1 = (v1 - mu)*inv*lng[c0+1] + lnb[c0+1];
  uint ow = (uint)f2bf(leaky(y0)) | ((uint)f2bf(leaky(y1)) << 16);
  *(uint*)(outH + (size_t)dd*128 + c0) = ow;
}

// ---------------- GAT output layer (1 head, 67 cols), bf16 gathers + residual ----------------
__global__ __launch_bounds__(256) void k_gat_out(const ushort* __restrict__ ht2,
    const float* __restrict__ alS, const float* __restrict__ alD,
    const int* __restrict__ deg, const ushort* __restrict__ slot,
    const float* __restrict__ gb2, const float* __restrict__ x,
    const float* __restrict__ pos, float* __restrict__ out, int n){
  __shared__ float wbuf[4][64];
  __shared__ int   sbuf[4][64];
  int wave = threadIdx.x >> 6, lane = threadIdx.x & 63;
  int dd = blockIdx.x*4 + wave;
  if (dd >= n) return;
  int tr  = (dd >= Nn) ? dd - Nn : dd;
  int off = (dd >= Nn) ? Nn : 0;
  int c0 = lane*2;
  bool act = (c0 < 67);             // lane < 34
  float ald = alD[dd];
  int dg = deg[tr]; if (dg > STRIDE) dg = STRIDE;
  int begin = tr*STRIDE, end = begin + dg;

  // self-loop term
  float wsl = __expf(leaky(alS[dd] + ald));
  float den  = wsl;
  uint sv0 = act ? *(const uint*)(ht2 + (size_t)dd*68 + c0) : 0u;
  float acc0 = wsl * bf2f((ushort)(sv0 & 0xffff));
  float acc1 = wsl * bf2f((ushort)(sv0 >> 16));

  const ushort* __restrict__ h2p = ht2 + c0;

  for (int j = begin; j < end; j += 64){
    int nc = min(64, end - j);
    if (lane < nc){
      int s = (int)slot[j + lane] + off;
      wbuf[wave][lane] = __expf(leaky(alS[s] + ald));
      sbuf[wave][lane] = s;
    }
    int q = 0;
    for (; q + 8 <= nc; q += 8){
      int sv[8]; float wv[8];
      #pragma unroll
      for (int u=0;u<8;u++){ sv[u] = sbuf[wave][q+u]; wv[u] = wbuf[wave][q+u]; }
      uint hv[8];
      #pragma unroll
      for (int u=0;u<8;u++) hv[u] = act ? *(const uint*)(h2p + (size_t)sv[u]*68) : 0u;
      #pragma unroll
      for (int u=0;u<8;u++){
        den  += wv[u];
        acc0 += wv[u] * bf2f((ushort)(hv[u] & 0xffff));
        acc1 += wv[u] * bf2f((ushort)(hv[u] >> 16));
      }
    }
    for (; q < nc; q++){
      int s = sbuf[wave][q]; float w = wbuf[wave][q];
      uint hv = act ? *(const uint*)(h2p + (size_t)s*68) : 0u;
      den  += w;
      acc0 += w * bf2f((ushort)(hv & 0xffff));
      acc1 += w * bf2f((ushort)(hv >> 16));
    }
  }
  if (!act) return;
  float idn = 1.f / (den + 1e-16f);
  int i = tr;
  int c1 = c0 + 1;
  float v0 = acc0*idn + gb2[c0];
  if (c0 < 3) out[NT*64 + dd*3 + c0] = pos[i*3 + c0] + v0;
  else        out[dd*64 + (c0-3)]    = x[i*64 + (c0-3)] + v0;
  if (c1 < 67){
    float v1 = acc1*idn + gb2[c1];
    if (c1 < 3) out[NT*64 + dd*3 + c1] = pos[i*3 + c1] + v1;
    else        out[dd*64 + (c1-3)]    = x[i*64 + (c1-3)] + v1;
  }
}

extern "C" void kernel_launch(void* const* d_in, const int* in_sizes, int n_in,
                              void* d_out, int out_size, void* d_ws, size_t ws_size,
                              hipStream_t stream){
  const float* z    = (const float*)d_in[0];
  const float* x    = (const float*)d_in[1];
  const float* pos  = (const float*)d_in[2];
  const int*   eidx = (const int*)  d_in[3];
  const float* w1   = (const float*)d_in[4];
  const float* b1   = (const float*)d_in[5];
  const float* w2   = (const float*)d_in[6];
  const float* b2   = (const float*)d_in[7];
  const float* w3   = (const float*)d_in[8];
  const float* b3   = (const float*)d_in[9];
  const float* gw0  = (const float*)d_in[10];
  const float* ga0s = (const float*)d_in[11];
  const float* ga0d = (const float*)d_in[12];
  const float* gb0  = (const float*)d_in[13];
  const float* gw1  = (const float*)d_in[14];
  const float* ga1s = (const float*)d_in[15];
  const float* ga1d = (const float*)d_in[16];
  const float* gb1  = (const float*)d_in[17];
  const float* gw2  = (const float*)d_in[18];
  const float* ga2s = (const float*)d_in[19];
  const float* ga2d = (const float*)d_in[20];
  const float* gb2  = (const float*)d_in[21];
  const float* ln0g = (const float*)d_in[22];
  const float* ln0b = (const float*)d_in[23];
  const float* ln1g = (const float*)d_in[24];
  const float* ln1b = (const float*)d_in[25];
  float* out = (float*)d_out;

  float* ws       = (float*)d_ws;
  float* styleW0  = ws;                  // 256
  float* s1buf    = ws + 256;            // 512
  float* s2buf    = s1buf + 512;         // 1024
  float* stbuf    = s2buf + 1024;        // 256
  float* alS      = stbuf + 256;         // 80000
  float* alD      = alS + 80000;         // 80000
  ushort* htA     = (ushort*)(alD + 80000);  // NT*128 bf16
  ushort* htB     = htA + (size_t)NT*128;    // NT*128 bf16
  ushort* ht2c    = htB + (size_t)NT*128;    // NT*68 bf16
  ushort* xb      = ht2c + (size_t)NT*68;    // Nn*64 bf16 (x converted)
  int*   cnt      = (int*)(xb + (size_t)Nn*64);   // Nn (degree)
  ushort* slot    = (ushort*)(cnt + Nn);          // Nn*STRIDE (padded CSR)

  // style path; first dispatch also zeroes cnt and converts x->bf16
  const int ZB = (Nn + 255)/256;           // 40 zero-blocks
  const int XB = (Nn*64/4 + 255)/256;      // 625 convert-blocks
  k_mlp<128><<<128 + ZB + XB, 256, 0, stream>>>(z, w1, b1, s1buf, 256, 1, 128,
                                                cnt, Nn, ZB, x, xb, Nn*64/4);
  k_mlp<256><<<256, 256, 0, stream>>>(s1buf, w2, b2, s2buf, 512, 1, 256,
                                      nullptr, 0, 0, nullptr, nullptr, 0);
  k_mlp<512><<<64,  256, 0, stream>>>(s2buf, w3, b3, stbuf, 128, 0, 64,
                                      nullptr, 0, 0, nullptr, nullptr, 0);
  k_mlp<128><<<64,  256, 0, stream>>>(stbuf, gw0 + 64*128, (const float*)nullptr,
                                      styleW0, 128, 0, 64,
                                      nullptr, 0, 0, nullptr, nullptr, 0);

  const int MB0 = (Nn+127)/128;            // 79 mfma blocks
  const int EB  = (Me+255)/256;            // 1250 scatter blocks
  // layer 0: ht0 MFMA + fused logits, with CSR scatter in extra blocks
  k_ht0_mfma<<<MB0 + EB, 256, 0, stream>>>(xb, gw0, styleW0, ga0s, ga0d,
                                           htA, alS, alD, MB0, eidx, cnt, slot);
  k_gat128<<<(NT+3)/4, 256, 0, stream>>>(htA, alS, alD, cnt, slot,
                                         gb0, ln0g, ln0b, htB, NT);
  // layer 1 (matmul + fused logits)
  const int MB = (NT+127)/128;
  k_mm_mfma<128,128,8,4><<<MB, 256, 0, stream>>>(htB, gw1, htA, ga1s, ga1d, alS, alD, NT);
  k_gat128<<<(NT+3)/4, 256, 0, stream>>>(htA, alS, alD, cnt, slot,
                                         gb1, ln1g, ln1b, htB, NT);
  // layer 2 (matmul + fused logits, 1 head; then fused residual + final write)
  k_mm_mfma<67,68,5,1><<<MB, 256, 0, stream>>>(htB, gw2, ht2c, ga2s, ga2d, alS, alD, NT);
  k_gat_out<<<(NT+3)/4, 256, 0, stream>>>(ht2c, alS, alD, cnt, slot,
                                          gb2, x, pos, out, NT);
}